// Round 10
// baseline (339.849 us; speedup 1.0000x reference)
//
#include <hip/hip_runtime.h>
#include <hip/hip_bf16.h>

#define DIN 64
#define DH 128
#define EPSF 1e-5f
#define SLOPE 0.1f

typedef unsigned short u16;
typedef unsigned int u32;
typedef unsigned long long u64;
typedef __attribute__((ext_vector_type(8))) short bf16x8;
typedef __attribute__((ext_vector_type(4))) float f32x4;

#define FIXS 16777216.0f   // 2^24 fixed-point scale for edge weights
#define LDA1 136           // padded LDS row stride (bf16), K=128 tiles
#define LDA0 72            // padded LDS row stride, K=64 tiles

__device__ __forceinline__ float bf2f(u16 u){
    union { u32 i; float f; } v; v.i = ((u32)u) << 16; return v.f;
}
__device__ __forceinline__ u16 f2bf(float f){
    union { float f; u32 i; } v; v.f = f;
    u32 b = v.i;
    b += 0x7FFFu + ((b >> 16) & 1u);    // round to nearest even
    return (u16)(b >> 16);
}
__device__ __forceinline__ u32 pack2(float a, float b){
    return (u32)f2bf(a) | ((u32)f2bf(b) << 16);
}

// ---------------- graph prep ----------------

__global__ void k_init(u64* packed, int N){
    int i = blockIdx.x * 256 + threadIdx.x;
    if (i < N) packed[i] = 0ull;
}

// ONE returning u64 atomic per edge; 8 edges/thread -> ~96 atomics in flight per CU
// (12 waves/CU x 8-deep). count in bits[40..], fixed-point ew sum in bits[0..40).
__global__ void k_count(const int* __restrict__ dst, const float* __restrict__ ew,
                        u64* packed, int* __restrict__ slotl, int E){
    int base = blockIdx.x * 2048 + threadIdx.x;
    int  e[8]; bool v[8]; int d[8]; float w[8]; u64 o[8];
    #pragma unroll
    for (int k = 0; k < 8; k++){
        e[k] = base + k * 256;
        v[k] = e[k] < E;
        d[k] = 0; w[k] = 0.0f;
        if (v[k]){ d[k] = dst[e[k]]; w[k] = ew[e[k]]; }
    }
    #pragma unroll
    for (int k = 0; k < 8; k++){
        o[k] = 0;
        if (v[k])
            o[k] = atomicAdd(&packed[d[k]],
                             (1ull << 40) | (u64)(u32)__float2int_rn(w[k] * FIXS));
    }
    #pragma unroll
    for (int k = 0; k < 8; k++)
        if (v[k]) slotl[e[k]] = (int)(o[k] >> 40);
}

// phase 1: per-1024-block LOCAL exclusive scan of counts; fused dinv
__global__ __launch_bounds__(1024) void k_scan1d(const u64* __restrict__ packed,
        float* __restrict__ dinv, int* __restrict__ rowstart,
        int* __restrict__ blocksum, int N){
    __shared__ int lds[1024];
    int t = threadIdx.x;
    int i = blockIdx.x * 1024 + t;
    int v = 0;
    if (i < N){
        u64 p = packed[i];
        float deg = 1.0f + (float)(p & 0xFFFFFFFFFFull) * (1.0f / FIXS);
        dinv[i] = rsqrtf(deg);               // deg >= 1 (self-loop)
        v = (int)(p >> 40);
    }
    lds[t] = v;
    __syncthreads();
    for (int off = 1; off < 1024; off <<= 1){
        int add = (t >= off) ? lds[t - off] : 0;
        __syncthreads();
        lds[t] += add;
        __syncthreads();
    }
    if (i < N) rowstart[i] = lds[t] - v;            // block-local exclusive
    if (t == 1023) blocksum[blockIdx.x] = lds[1023];
}

// phase 2: exclusive-scan block sums into blocksum[0..1023]; write adjusted
// rowstart[N] (local form: global = local + blocksum[i>>10]); zero BN stats.
__global__ __launch_bounds__(1024) void k_scan2(int* __restrict__ blocksum,
        int* __restrict__ rowstart, float* __restrict__ stats, int nb, int N, int E){
    __shared__ int lds[1024];
    int t = threadIdx.x;
    if (t < 512) stats[t] = 0.0f;                   // sum0,sq0,sum1,sq1
    int v = (t < nb) ? blocksum[t] : 0;
    lds[t] = v;
    __syncthreads();
    for (int off = 1; off < 1024; off <<= 1){
        int add = (t >= off) ? lds[t - off] : 0;
        __syncthreads();
        lds[t] += add;
        __syncthreads();
    }
    blocksum[t] = lds[t] - v;                       // exclusive offsets, all t
    if (t == (N >> 10)) rowstart[N] = E - (lds[t] - v);
}

// place edge data, 8 edges/thread; slot = rowst_local[d] + blocksum[d>>10] + slotl; NO atomics.
__global__ void k_place(const int* __restrict__ src, const int* __restrict__ dst,
                        const float* __restrict__ ew, const float* __restrict__ dinv,
                        const int* __restrict__ rowst, const int* __restrict__ blocksum,
                        const int* __restrict__ slotl, u64* __restrict__ edata, int E){
    int base = blockIdx.x * 2048 + threadIdx.x;
    #pragma unroll
    for (int u = 0; u < 8; u++){
        int e = base + u * 256;
        if (e < E){
            int s = src[e], d = dst[e];
            union { float f; u32 i; } c;
            c.f = dinv[s] * ew[e] * dinv[d];
            int slot = rowst[d] + blocksum[d >> 10] + slotl[e];
            edata[slot] = (u64)(u32)s | ((u64)c.i << 32);
        }
    }
}

// ---------------- GEMM 0 (MFMA bf16): h0 = x@W0, res = x@Wres + bres ----------------

__global__ __launch_bounds__(256) void k_gemm0(const float* __restrict__ x,
        const float* __restrict__ W0, const float* __restrict__ Wres,
        const float* __restrict__ bres, u16* __restrict__ h0,
        u16* __restrict__ res, int N){
    __shared__ u16 xs[64 * LDA0];    // 9 KB
    __shared__ u16 ws[256 * LDA0];   // 36.9 KB
    int tid = threadIdx.x;
    int row0 = blockIdx.x * 64;
    for (int i = tid; i < 256 * 32; i += 256){
        int n = i & 255, k = (i >> 8) * 2;
        int c = n & 127;
        const float* __restrict__ W = (n < 128) ? W0 : Wres;
        float wa = W[k * DH + c], wb = W[(k + 1) * DH + c];
        *(u32*)&ws[n * LDA0 + k] = pack2(wa, wb);
    }
    for (int i = tid; i < 64 * 32; i += 256){
        int r = i >> 5, k2 = (i & 31) * 2;
        int rr = row0 + r; if (rr >= N) rr = N - 1;
        float2 v = *(const float2*)&x[(size_t)rr * DIN + k2];
        *(u32*)&xs[r * LDA0 + k2] = pack2(v.x, v.y);
    }
    __syncthreads();
    int wave = tid >> 6, lane = tid & 63;
    int l15 = lane & 15, kq = (lane >> 4) * 8;
    f32x4 acc[16];
    #pragma unroll
    for (int nt = 0; nt < 16; nt++) acc[nt] = (f32x4){0.f, 0.f, 0.f, 0.f};
    #pragma unroll
    for (int kt = 0; kt < 2; kt++){
        int k0 = kt * 32 + kq;
        bf16x8 a = *(const bf16x8*)&xs[(wave * 16 + l15) * LDA0 + k0];
        #pragma unroll
        for (int nt = 0; nt < 16; nt++){
            bf16x8 b = *(const bf16x8*)&ws[(nt * 16 + l15) * LDA0 + k0];
            acc[nt] = __builtin_amdgcn_mfma_f32_16x16x32_bf16(a, b, acc[nt], 0, 0, 0);
        }
    }
    int rbase = row0 + wave * 16 + (lane >> 4) * 4;
    #pragma unroll
    for (int nt = 0; nt < 16; nt++){
        int col = nt * 16 + l15;
        #pragma unroll
        for (int reg = 0; reg < 4; reg++){
            int rr = rbase + reg;
            if (rr < N){
                if (col < DH) h0[(size_t)rr * DH + col] = f2bf(acc[nt][reg]);
                else          res[(size_t)rr * DH + (col - DH)] = f2bf(acc[nt][reg] + bres[col - DH]);
            }
        }
    }
}

// ---------------- GEMM 1 (MFMA bf16, fused BN+leaky+residual on input) ----------------

__global__ __launch_bounds__(256) void k_gemm1f(const u16* __restrict__ Bi,
        const u16* __restrict__ Ri, const float* __restrict__ sum,
        const float* __restrict__ sq, const float* __restrict__ g,
        const float* __restrict__ be, const float* __restrict__ W1,
        u16* __restrict__ A, int N, float invN){
    __shared__ u16 xs[64 * LDA1];    // 17.4 KB
    __shared__ u16 ws[128 * LDA1];   // 34.8 KB
    __shared__ float sc[DH], sh[DH];
    int tid = threadIdx.x;
    if (tid < DH){
        float mean = sum[tid] * invN;
        float var  = sq[tid] * invN - mean * mean;
        float s = g[tid] * rsqrtf(var + EPSF);
        sc[tid] = s;
        sh[tid] = be[tid] - mean * s;
    }
    for (int i = tid; i < 128 * 64; i += 256){
        int n = i & 127, k = (i >> 7) * 2;
        float wa = W1[k * DH + n], wb = W1[(k + 1) * DH + n];
        *(u32*)&ws[n * LDA1 + k] = pack2(wa, wb);
    }
    __syncthreads();
    int row0 = blockIdx.x * 64;
    for (int i = tid; i < 64 * 64; i += 256){
        int r = i >> 6, k2 = (i & 63) * 2;
        int rr = row0 + r;
        u32 o = 0;
        if (rr < N){
            u32 bu = *(const u32*)&Bi[(size_t)rr * DH + k2];
            u32 ru = *(const u32*)&Ri[(size_t)rr * DH + k2];
            float t0 = bf2f((u16)bu) * sc[k2] + sh[k2];
            t0 = ((t0 >= 0.f) ? t0 : SLOPE * t0) + bf2f((u16)ru);
            float t1 = bf2f((u16)(bu >> 16)) * sc[k2 + 1] + sh[k2 + 1];
            t1 = ((t1 >= 0.f) ? t1 : SLOPE * t1) + bf2f((u16)(ru >> 16));
            o = pack2(t0, t1);
        }
        *(u32*)&xs[r * LDA1 + k2] = o;
    }
    __syncthreads();
    int wave = tid >> 6, lane = tid & 63;
    int l15 = lane & 15, kq = (lane >> 4) * 8;
    f32x4 acc[8];
    #pragma unroll
    for (int nt = 0; nt < 8; nt++) acc[nt] = (f32x4){0.f, 0.f, 0.f, 0.f};
    #pragma unroll
    for (int kt = 0; kt < 4; kt++){
        int k0 = kt * 32 + kq;
        bf16x8 a = *(const bf16x8*)&xs[(wave * 16 + l15) * LDA1 + k0];
        #pragma unroll
        for (int nt = 0; nt < 8; nt++){
            bf16x8 b = *(const bf16x8*)&ws[(nt * 16 + l15) * LDA1 + k0];
            acc[nt] = __builtin_amdgcn_mfma_f32_16x16x32_bf16(a, b, acc[nt], 0, 0, 0);
        }
    }
    int rbase = row0 + wave * 16 + (lane >> 4) * 4;
    #pragma unroll
    for (int nt = 0; nt < 8; nt++){
        int col = nt * 16 + l15;
        #pragma unroll
        for (int reg = 0; reg < 4; reg++){
            int rr = rbase + reg;
            if (rr < N) A[(size_t)rr * DH + col] = f2bf(acc[nt][reg]);
        }
    }
}

// ---------------- aggregation: HALF-wave per node (32 lanes x u64), 8-deep ----------------
// 256 threads = 8 nodes/block; up to 16 gather chains in flight per wave.

__device__ __forceinline__ void agg_edge4(const u16* __restrict__ hin, u64 e,
                                          int col, float& a0, float& a1,
                                          float& a2, float& a3){
    union { u32 i; float f; } c;
    c.i = (u32)(e >> 32);
    u64 u = *(const u64*)&hin[(size_t)(u32)e * DH + col];
    a0 += c.f * bf2f((u16)u);
    a1 += c.f * bf2f((u16)(u >> 16));
    a2 += c.f * bf2f((u16)(u >> 32));
    a3 += c.f * bf2f((u16)(u >> 48));
}

__global__ __launch_bounds__(256) void k_aggregate(const u16* __restrict__ hin,
        u16* __restrict__ out, const float* __restrict__ bias,
        const float* __restrict__ dinv, const int* __restrict__ rowstart,
        const int* __restrict__ blocksum, const u64* __restrict__ edata, int N){
    int tid = threadIdx.x;
    int lane = tid & 63;
    int half = lane >> 5, hl = lane & 31;
    int node = blockIdx.x * 8 + (tid >> 6) * 2 + half;
    if (node >= N) return;
    int col = hl * 4;
    float dn = dinv[node];
    float scf = dn * dn;                      // self-loop coefficient
    u64 hu = *(const u64*)&hin[(size_t)node * DH + col];
    float4 bv = *(const float4*)&bias[col];
    float a0 = bv.x + scf * bf2f((u16)hu);
    float a1 = bv.y + scf * bf2f((u16)(hu >> 16));
    float a2 = bv.z + scf * bf2f((u16)(hu >> 32));
    float a3 = bv.w + scf * bf2f((u16)(hu >> 48));
    int rs = rowstart[node]     + blocksum[node >> 10];
    int re = rowstart[node + 1] + blocksum[(node + 1) >> 10];
    int j = rs;
    for (; j + 7 < re; j += 8){
        u64 e0 = edata[j],     e1 = edata[j + 1], e2 = edata[j + 2], e3 = edata[j + 3];
        u64 e4 = edata[j + 4], e5 = edata[j + 5], e6 = edata[j + 6], e7 = edata[j + 7];
        agg_edge4(hin, e0, col, a0, a1, a2, a3); agg_edge4(hin, e1, col, a0, a1, a2, a3);
        agg_edge4(hin, e2, col, a0, a1, a2, a3); agg_edge4(hin, e3, col, a0, a1, a2, a3);
        agg_edge4(hin, e4, col, a0, a1, a2, a3); agg_edge4(hin, e5, col, a0, a1, a2, a3);
        agg_edge4(hin, e6, col, a0, a1, a2, a3); agg_edge4(hin, e7, col, a0, a1, a2, a3);
    }
    if (j + 3 < re){
        u64 e0 = edata[j], e1 = edata[j + 1], e2 = edata[j + 2], e3 = edata[j + 3];
        agg_edge4(hin, e0, col, a0, a1, a2, a3); agg_edge4(hin, e1, col, a0, a1, a2, a3);
        agg_edge4(hin, e2, col, a0, a1, a2, a3); agg_edge4(hin, e3, col, a0, a1, a2, a3);
        j += 4;
    }
    for (; j < re; j++)
        agg_edge4(hin, edata[j], col, a0, a1, a2, a3);
    u64 ov = (u64)pack2(a0, a1) | ((u64)pack2(a2, a3) << 32);
    *(u64*)&out[(size_t)node * DH + col] = ov;
}

// ---------------- batchnorm stats (bf16 input via u32 loads, f32 sums) ----------------

__global__ __launch_bounds__(256) void k_bnstats(const u16* __restrict__ h,
        float* sum, float* sq, int N, int rpb){
    __shared__ float rs[4][DH], rq[4][DH];
    int tid = threadIdx.x;
    int lane = tid & 63, wave = tid >> 6;
    int c = 2 * lane;
    int r0 = blockIdx.x * rpb;
    int r1 = r0 + rpb; if (r1 > N) r1 = N;
    float s0 = 0.0f, s1 = 0.0f, q0 = 0.0f, q1 = 0.0f;
    for (int r = r0 + wave; r < r1; r += 4){
        u32 u = *(const u32*)&h[(size_t)r * DH + c];
        float v0 = bf2f((u16)u), v1 = bf2f((u16)(u >> 16));
        s0 += v0; s1 += v1; q0 += v0 * v0; q1 += v1 * v1;
    }
    rs[wave][c] = s0; rs[wave][c + 1] = s1;
    rq[wave][c] = q0; rq[wave][c + 1] = q1;
    __syncthreads();
    if (tid < DH){
        atomicAdd(&sum[tid], rs[0][tid] + rs[1][tid] + rs[2][tid] + rs[3][tid]);
        atomicAdd(&sq[tid],  rq[0][tid] + rq[1][tid] + rq[2][tid] + rq[3][tid]);
    }
}

// ---------------- final: BN apply + leaky + residual + layernorm + store ----------------

__global__ __launch_bounds__(256) void k_lnf(const u16* __restrict__ B,
        const u16* __restrict__ R, const float* __restrict__ sum,
        const float* __restrict__ sq, const float* __restrict__ g,
        const float* __restrict__ be, float* __restrict__ out, int N, float invN){
    int node = blockIdx.x * 4 + (threadIdx.x >> 6);
    int lane = threadIdx.x & 63;
    if (node >= N) return;
    int col = 2 * lane;
    float2 sm  = *(const float2*)&sum[col];
    float2 sqv = *(const float2*)&sq[col];
    float2 gv  = *(const float2*)&g[col];
    float2 bev = *(const float2*)&be[col];
    float m0 = sm.x * invN, m1 = sm.y * invN;
    float va0 = sqv.x * invN - m0 * m0, va1 = sqv.y * invN - m1 * m1;
    float s0 = gv.x * rsqrtf(va0 + EPSF), s1 = gv.y * rsqrtf(va1 + EPSF);
    float h0 = bev.x - m0 * s0, h1 = bev.y - m1 * s1;
    u32 bu = *(const u32*)&B[(size_t)node * DH + col];
    u32 ru = *(const u32*)&R[(size_t)node * DH + col];
    float t0 = bf2f((u16)bu) * s0 + h0;
    t0 = ((t0 >= 0.0f) ? t0 : SLOPE * t0) + bf2f((u16)ru);
    float t1 = bf2f((u16)(bu >> 16)) * s1 + h1;
    t1 = ((t1 >= 0.0f) ? t1 : SLOPE * t1) + bf2f((u16)(ru >> 16));
    float s = t0 + t1;
    float q = t0 * t0 + t1 * t1;
    #pragma unroll
    for (int off = 1; off < 64; off <<= 1){
        s += __shfl_xor(s, off, 64);
        q += __shfl_xor(q, off, 64);
    }
    float mean = s * (1.0f / DH);
    float var  = q * (1.0f / DH) - mean * mean;
    float rstd = rsqrtf(var + EPSF);
    float2 o;
    o.x = (t0 - mean) * rstd;
    o.y = (t1 - mean) * rstd;
    *(float2*)&out[(size_t)node * DH + col] = o;
}

// ---------------- launch ----------------

extern "C" void kernel_launch(void* const* d_in, const int* in_sizes, int n_in,
                              void* d_out, int out_size, void* d_ws, size_t ws_size,
                              hipStream_t stream){
    const float* x    = (const float*)d_in[0];
    const int*   src  = (const int*)d_in[1];
    const int*   dst  = (const int*)d_in[2];
    const float* ew   = (const float*)d_in[3];
    const float* W0   = (const float*)d_in[4];
    const float* b0   = (const float*)d_in[5];
    const float* g0   = (const float*)d_in[6];
    const float* be0  = (const float*)d_in[7];
    const float* W1   = (const float*)d_in[8];
    const float* b1   = (const float*)d_in[9];
    const float* g1   = (const float*)d_in[10];
    const float* be1  = (const float*)d_in[11];
    const float* Wres = (const float*)d_in[12];
    const float* bres = (const float*)d_in[13];
    float* out = (float*)d_out;

    int N = in_sizes[0] / DIN;
    int E = in_sizes[1];
    size_t N128 = (size_t)N * DH;
    float invN = 1.0f / (float)N;

    // workspace layout
    u16* A = (u16*)d_ws;                 // gemm outputs, bf16 [N128]
    u16* B = A + N128;                   // agg outputs, bf16 [N128]
    u16* R = B + N128;                   // residual, bf16 [N128]
    u64* packed = (u64*)(R + N128);      // [N] count<<40 | fixed ew sum
    u64* edata  = packed + N;            // [E] src | coef<<32
    float* dinv = (float*)(edata + E);   // [N]
    int* rowst  = (int*)(dinv + N);      // [N+1] (block-local until blocksum added)
    int* slotl  = rowst + N + 1;         // [E]
    float* stats = (float*)(slotl + E);  // 4*DH
    float* sum0 = stats,          *sq0 = stats + DH;
    float* sum1 = stats + 2 * DH, *sq1 = stats + 3 * DH;
    int* blocksum = (int*)(stats + 4 * DH);  // [1024]

    int nb  = (N + 255) / 256;
    int eb8 = (E + 2047) / 2048;
    int gb  = (N + 63) / 64;
    int ab8 = (N + 7) / 8;
    int ab4 = (N + 3) / 4;
    int kb  = (N + 1023) / 1024;
    int rpb = 250;
    int sb  = (N + rpb - 1) / rpb;

    k_init   <<<nb, 256, 0, stream>>>(packed, N);
    k_count  <<<eb8, 256, 0, stream>>>(dst, ew, packed, slotl, E);
    k_scan1d <<<kb, 1024, 0, stream>>>(packed, dinv, rowst, blocksum, N);
    k_scan2  <<<1, 1024, 0, stream>>>(blocksum, rowst, stats, kb, N, E);
    k_place  <<<eb8, 256, 0, stream>>>(src, dst, ew, dinv, rowst, blocksum, slotl, edata, E);

    // layer 0
    k_gemm0    <<<gb, 256, 0, stream>>>(x, W0, Wres, bres, A, R, N);
    k_aggregate<<<ab8, 256, 0, stream>>>(A, B, b0, dinv, rowst, blocksum, edata, N);
    k_bnstats  <<<sb, 256, 0, stream>>>(B, sum0, sq0, N, rpb);

    // layer 1 (BN0+leaky+residual fused into gemm1 tile load)
    k_gemm1f   <<<gb, 256, 0, stream>>>(B, R, sum0, sq0, g0, be0, W1, A, N, invN);
    k_aggregate<<<ab8, 256, 0, stream>>>(A, B, b1, dinv, rowst, blocksum, edata, N);
    k_bnstats  <<<sb, 256, 0, stream>>>(B, sum1, sq1, N, rpb);

    // BN1+leaky+residual + layernorm fused
    k_lnf      <<<ab4, 256, 0, stream>>>(B, R, sum1, sq1, g1, be1, out, N, invN);
}

// Round 11
// 332.799 us; speedup vs baseline: 1.0212x; 1.0212x over previous
//
#include <hip/hip_runtime.h>
#include <hip/hip_bf16.h>

#define DIN 64
#define DH 128
#define EPSF 1e-5f
#define SLOPE 0.1f

typedef unsigned short u16;
typedef unsigned int u32;
typedef unsigned long long u64;
typedef __attribute__((ext_vector_type(8))) short bf16x8;
typedef __attribute__((ext_vector_type(4))) float f32x4;

#define FIXS 16777216.0f   // 2^24 fixed-point scale for edge weights
#define LDA1 136           // padded LDS row stride (bf16), K=128 tiles
#define LDA0 72            // padded LDS row stride, K=64 tiles

__device__ __forceinline__ float bf2f(u16 u){
    union { u32 i; float f; } v; v.i = ((u32)u) << 16; return v.f;
}
__device__ __forceinline__ u16 f2bf(float f){
    union { float f; u32 i; } v; v.f = f;
    u32 b = v.i;
    b += 0x7FFFu + ((b >> 16) & 1u);    // round to nearest even
    return (u16)(b >> 16);
}
__device__ __forceinline__ u32 pack2(float a, float b){
    return (u32)f2bf(a) | ((u32)f2bf(b) << 16);
}

// ---------------- FAT kernel: count (atomic-bound) + gemm0 (VALU/MFMA-bound) ----------------
// blocks [0, eb8): one returning u64 atomic per edge, 8 edges/thread.
// blocks [eb8, ...): gemm0 tiles — co-scheduled into count's idle pipes.

__global__ __launch_bounds__(256) void k_cnt_gemm0(
        const int* __restrict__ dst, const float* __restrict__ ew,
        u64* packed, int* __restrict__ slotl, int E, int eb8,
        const float* __restrict__ x, const float* __restrict__ W0,
        const float* __restrict__ Wres, const float* __restrict__ bres,
        u16* __restrict__ h0, u16* __restrict__ res, int N){
    __shared__ u16 xs[64 * LDA0];    // 9 KB
    __shared__ u16 ws[256 * LDA0];   // 36.9 KB
    int tid = threadIdx.x;
    if ((int)blockIdx.x < eb8){
        // ---- count ----
        int base = blockIdx.x * 2048 + tid;
        int  e[8]; bool v[8]; int d[8]; float w[8]; u64 o[8];
        #pragma unroll
        for (int k = 0; k < 8; k++){
            e[k] = base + k * 256;
            v[k] = e[k] < E;
            d[k] = 0; w[k] = 0.0f;
            if (v[k]){ d[k] = dst[e[k]]; w[k] = ew[e[k]]; }
        }
        #pragma unroll
        for (int k = 0; k < 8; k++){
            o[k] = 0;
            if (v[k])
                o[k] = atomicAdd(&packed[d[k]],
                                 (1ull << 40) | (u64)(u32)__float2int_rn(w[k] * FIXS));
        }
        #pragma unroll
        for (int k = 0; k < 8; k++)
            if (v[k]) slotl[e[k]] = (int)(o[k] >> 40);
        return;
    }
    // ---- gemm0: h0 = x@W0, res = x@Wres + bres ----
    int row0 = (blockIdx.x - eb8) * 64;
    for (int i = tid; i < 256 * 32; i += 256){
        int n = i & 255, k = (i >> 8) * 2;
        int c = n & 127;
        const float* __restrict__ W = (n < 128) ? W0 : Wres;
        float wa = W[k * DH + c], wb = W[(k + 1) * DH + c];
        *(u32*)&ws[n * LDA0 + k] = pack2(wa, wb);
    }
    for (int i = tid; i < 64 * 32; i += 256){
        int r = i >> 5, k2 = (i & 31) * 2;
        int rr = row0 + r; if (rr >= N) rr = N - 1;
        float2 v = *(const float2*)&x[(size_t)rr * DIN + k2];
        *(u32*)&xs[r * LDA0 + k2] = pack2(v.x, v.y);
    }
    __syncthreads();
    int wave = tid >> 6, lane = tid & 63;
    int l15 = lane & 15, kq = (lane >> 4) * 8;
    f32x4 acc[16];
    #pragma unroll
    for (int nt = 0; nt < 16; nt++) acc[nt] = (f32x4){0.f, 0.f, 0.f, 0.f};
    #pragma unroll
    for (int kt = 0; kt < 2; kt++){
        int k0 = kt * 32 + kq;
        bf16x8 a = *(const bf16x8*)&xs[(wave * 16 + l15) * LDA0 + k0];
        #pragma unroll
        for (int nt = 0; nt < 16; nt++){
            bf16x8 b = *(const bf16x8*)&ws[(nt * 16 + l15) * LDA0 + k0];
            acc[nt] = __builtin_amdgcn_mfma_f32_16x16x32_bf16(a, b, acc[nt], 0, 0, 0);
        }
    }
    int rbase = row0 + wave * 16 + (lane >> 4) * 4;
    #pragma unroll
    for (int nt = 0; nt < 16; nt++){
        int col = nt * 16 + l15;
        #pragma unroll
        for (int reg = 0; reg < 4; reg++){
            int rr = rbase + reg;
            if (rr < N){
                if (col < DH) h0[(size_t)rr * DH + col] = f2bf(acc[nt][reg]);
                else          res[(size_t)rr * DH + (col - DH)] = f2bf(acc[nt][reg] + bres[col - DH]);
            }
        }
    }
}

// ---------------- merged scan: per-block local scan + last-block global pass ----------------
// Last arriving block (device-scope ticket) scans the <=64 block sums in one wave,
// publishes exclusive offsets (agent-scope atomics), sets rowstart[N], zeroes stats.

__global__ __launch_bounds__(1024) void k_scan(const u64* __restrict__ packed,
        u32* ticket, float* __restrict__ dinv, int* __restrict__ rowstart,
        int* __restrict__ blocksum, float* __restrict__ stats, int N, int E){
    __shared__ int lds[1024];
    __shared__ int flag;
    int t = threadIdx.x;
    int i = blockIdx.x * 1024 + t;
    int v = 0;
    if (i < N){
        u64 p = packed[i];
        float deg = 1.0f + (float)(p & 0xFFFFFFFFFFull) * (1.0f / FIXS);
        dinv[i] = rsqrtf(deg);               // deg >= 1 (self-loop)
        v = (int)(p >> 40);
    }
    lds[t] = v;
    __syncthreads();
    for (int off = 1; off < 1024; off <<= 1){
        int add = (t >= off) ? lds[t - off] : 0;
        __syncthreads();
        lds[t] += add;
        __syncthreads();
    }
    if (i < N) rowstart[i] = lds[t] - v;            // block-local exclusive
    if (t == 1023){
        __hip_atomic_store(&blocksum[blockIdx.x], lds[1023],
                           __ATOMIC_RELEASE, __HIP_MEMORY_SCOPE_AGENT);
        u32 old = __hip_atomic_fetch_add(ticket, 1u,
                           __ATOMIC_ACQ_REL, __HIP_MEMORY_SCOPE_AGENT);
        flag = (old == gridDim.x - 1);
    }
    __syncthreads();
    if (!flag) return;
    // ---- last block only: global phase ----
    if (t < 512) stats[t] = 0.0f;                   // sum0,sq0,sum1,sq1
    if (t < 64){
        int nb = (int)gridDim.x;
        int bv = 0;
        if (t < nb) bv = __hip_atomic_load(&blocksum[t],
                              __ATOMIC_ACQUIRE, __HIP_MEMORY_SCOPE_AGENT);
        int incl = bv;
        #pragma unroll
        for (int off = 1; off < 64; off <<= 1){
            int up = __shfl_up(incl, off, 64);
            if (t >= off) incl += up;
        }
        int excl = incl - bv;
        __hip_atomic_store(&blocksum[t], excl,
                           __ATOMIC_RELEASE, __HIP_MEMORY_SCOPE_AGENT);
        if (t == (N >> 10)) rowstart[N] = E - excl;
    }
}

// ---------------- place edge data, 8 edges/thread; NO atomics ----------------

__global__ void k_place(const int* __restrict__ src, const int* __restrict__ dst,
                        const float* __restrict__ ew, const float* __restrict__ dinv,
                        const int* __restrict__ rowst, const int* __restrict__ blocksum,
                        const int* __restrict__ slotl, u64* __restrict__ edata, int E){
    int base = blockIdx.x * 2048 + threadIdx.x;
    #pragma unroll
    for (int u = 0; u < 8; u++){
        int e = base + u * 256;
        if (e < E){
            int s = src[e], d = dst[e];
            union { float f; u32 i; } c;
            c.f = dinv[s] * ew[e] * dinv[d];
            int slot = rowst[d] + blocksum[d >> 10] + slotl[e];
            edata[slot] = (u64)(u32)s | ((u64)c.i << 32);
        }
    }
}

// ---------------- GEMM 1 (MFMA bf16, fused BN+leaky+residual on input) ----------------

__global__ __launch_bounds__(256) void k_gemm1f(const u16* __restrict__ Bi,
        const u16* __restrict__ Ri, const float* __restrict__ sum,
        const float* __restrict__ sq, const float* __restrict__ g,
        const float* __restrict__ be, const float* __restrict__ W1,
        u16* __restrict__ A, int N, float invN){
    __shared__ u16 xs[64 * LDA1];    // 17.4 KB
    __shared__ u16 ws[128 * LDA1];   // 34.8 KB
    __shared__ float sc[DH], sh[DH];
    int tid = threadIdx.x;
    if (tid < DH){
        float mean = sum[tid] * invN;
        float var  = sq[tid] * invN - mean * mean;
        float s = g[tid] * rsqrtf(var + EPSF);
        sc[tid] = s;
        sh[tid] = be[tid] - mean * s;
    }
    for (int i = tid; i < 128 * 64; i += 256){
        int n = i & 127, k = (i >> 7) * 2;
        float wa = W1[k * DH + n], wb = W1[(k + 1) * DH + n];
        *(u32*)&ws[n * LDA1 + k] = pack2(wa, wb);
    }
    __syncthreads();
    int row0 = blockIdx.x * 64;
    for (int i = tid; i < 64 * 64; i += 256){
        int r = i >> 6, k2 = (i & 63) * 2;
        int rr = row0 + r;
        u32 o = 0;
        if (rr < N){
            u32 bu = *(const u32*)&Bi[(size_t)rr * DH + k2];
            u32 ru = *(const u32*)&Ri[(size_t)rr * DH + k2];
            float t0 = bf2f((u16)bu) * sc[k2] + sh[k2];
            t0 = ((t0 >= 0.f) ? t0 : SLOPE * t0) + bf2f((u16)ru);
            float t1 = bf2f((u16)(bu >> 16)) * sc[k2 + 1] + sh[k2 + 1];
            t1 = ((t1 >= 0.f) ? t1 : SLOPE * t1) + bf2f((u16)(ru >> 16));
            o = pack2(t0, t1);
        }
        *(u32*)&xs[r * LDA1 + k2] = o;
    }
    __syncthreads();
    int wave = tid >> 6, lane = tid & 63;
    int l15 = lane & 15, kq = (lane >> 4) * 8;
    f32x4 acc[8];
    #pragma unroll
    for (int nt = 0; nt < 8; nt++) acc[nt] = (f32x4){0.f, 0.f, 0.f, 0.f};
    #pragma unroll
    for (int kt = 0; kt < 4; kt++){
        int k0 = kt * 32 + kq;
        bf16x8 a = *(const bf16x8*)&xs[(wave * 16 + l15) * LDA1 + k0];
        #pragma unroll
        for (int nt = 0; nt < 8; nt++){
            bf16x8 b = *(const bf16x8*)&ws[(nt * 16 + l15) * LDA1 + k0];
            acc[nt] = __builtin_amdgcn_mfma_f32_16x16x32_bf16(a, b, acc[nt], 0, 0, 0);
        }
    }
    int rbase = row0 + wave * 16 + (lane >> 4) * 4;
    #pragma unroll
    for (int nt = 0; nt < 8; nt++){
        int col = nt * 16 + l15;
        #pragma unroll
        for (int reg = 0; reg < 4; reg++){
            int rr = rbase + reg;
            if (rr < N) A[(size_t)rr * DH + col] = f2bf(acc[nt][reg]);
        }
    }
}

// ---------------- aggregation: one wave per node, 8 gather chains (r9 form) ----------------

__device__ __forceinline__ void agg_edge(const u16* __restrict__ hin, u64 e,
                                         int col, float& ax, float& ay){
    union { u32 i; float f; } c;
    c.i = (u32)(e >> 32);
    u32 u = *(const u32*)&hin[(size_t)(u32)e * DH + col];
    ax += c.f * bf2f((u16)u);
    ay += c.f * bf2f((u16)(u >> 16));
}

__global__ __launch_bounds__(256) void k_aggregate(const u16* __restrict__ hin,
        u16* __restrict__ out, const float* __restrict__ bias,
        const float* __restrict__ dinv, const int* __restrict__ rowstart,
        const int* __restrict__ blocksum, const u64* __restrict__ edata, int N){
    int node = blockIdx.x * 4 + (threadIdx.x >> 6);
    int lane = threadIdx.x & 63;
    if (node >= N) return;
    float dn = dinv[node];
    float scf = dn * dn;                      // self-loop coefficient
    int col = 2 * lane;
    u32 hu = *(const u32*)&hin[(size_t)node * DH + col];
    float ax = bias[col]     + scf * bf2f((u16)hu);
    float ay = bias[col + 1] + scf * bf2f((u16)(hu >> 16));
    int rs = rowstart[node]     + blocksum[node >> 10];
    int re = rowstart[node + 1] + blocksum[(node + 1) >> 10];
    int j = rs;
    for (; j + 7 < re; j += 8){
        u64 e0 = edata[j],     e1 = edata[j + 1], e2 = edata[j + 2], e3 = edata[j + 3];
        u64 e4 = edata[j + 4], e5 = edata[j + 5], e6 = edata[j + 6], e7 = edata[j + 7];
        agg_edge(hin, e0, col, ax, ay); agg_edge(hin, e1, col, ax, ay);
        agg_edge(hin, e2, col, ax, ay); agg_edge(hin, e3, col, ax, ay);
        agg_edge(hin, e4, col, ax, ay); agg_edge(hin, e5, col, ax, ay);
        agg_edge(hin, e6, col, ax, ay); agg_edge(hin, e7, col, ax, ay);
    }
    if (j + 3 < re){
        u64 e0 = edata[j], e1 = edata[j + 1], e2 = edata[j + 2], e3 = edata[j + 3];
        agg_edge(hin, e0, col, ax, ay); agg_edge(hin, e1, col, ax, ay);
        agg_edge(hin, e2, col, ax, ay); agg_edge(hin, e3, col, ax, ay);
        j += 4;
    }
    for (; j < re; j++)
        agg_edge(hin, edata[j], col, ax, ay);
    *(u32*)&out[(size_t)node * DH + col] = pack2(ax, ay);
}

// ---------------- batchnorm stats (bf16 input via u32 loads, f32 sums) ----------------

__global__ __launch_bounds__(256) void k_bnstats(const u16* __restrict__ h,
        float* sum, float* sq, int N, int rpb){
    __shared__ float rs[4][DH], rq[4][DH];
    int tid = threadIdx.x;
    int lane = tid & 63, wave = tid >> 6;
    int c = 2 * lane;
    int r0 = blockIdx.x * rpb;
    int r1 = r0 + rpb; if (r1 > N) r1 = N;
    float s0 = 0.0f, s1 = 0.0f, q0 = 0.0f, q1 = 0.0f;
    for (int r = r0 + wave; r < r1; r += 4){
        u32 u = *(const u32*)&h[(size_t)r * DH + c];
        float v0 = bf2f((u16)u), v1 = bf2f((u16)(u >> 16));
        s0 += v0; s1 += v1; q0 += v0 * v0; q1 += v1 * v1;
    }
    rs[wave][c] = s0; rs[wave][c + 1] = s1;
    rq[wave][c] = q0; rq[wave][c + 1] = q1;
    __syncthreads();
    if (tid < DH){
        atomicAdd(&sum[tid], rs[0][tid] + rs[1][tid] + rs[2][tid] + rs[3][tid]);
        atomicAdd(&sq[tid],  rq[0][tid] + rq[1][tid] + rq[2][tid] + rq[3][tid]);
    }
}

// ---------------- final: BN apply + leaky + residual + layernorm + store ----------------

__global__ __launch_bounds__(256) void k_lnf(const u16* __restrict__ B,
        const u16* __restrict__ R, const float* __restrict__ sum,
        const float* __restrict__ sq, const float* __restrict__ g,
        const float* __restrict__ be, float* __restrict__ out, int N, float invN){
    int node = blockIdx.x * 4 + (threadIdx.x >> 6);
    int lane = threadIdx.x & 63;
    if (node >= N) return;
    int col = 2 * lane;
    float2 sm  = *(const float2*)&sum[col];
    float2 sqv = *(const float2*)&sq[col];
    float2 gv  = *(const float2*)&g[col];
    float2 bev = *(const float2*)&be[col];
    float m0 = sm.x * invN, m1 = sm.y * invN;
    float va0 = sqv.x * invN - m0 * m0, va1 = sqv.y * invN - m1 * m1;
    float s0 = gv.x * rsqrtf(va0 + EPSF), s1 = gv.y * rsqrtf(va1 + EPSF);
    float h0 = bev.x - m0 * s0, h1 = bev.y - m1 * s1;
    u32 bu = *(const u32*)&B[(size_t)node * DH + col];
    u32 ru = *(const u32*)&R[(size_t)node * DH + col];
    float t0 = bf2f((u16)bu) * s0 + h0;
    t0 = ((t0 >= 0.0f) ? t0 : SLOPE * t0) + bf2f((u16)ru);
    float t1 = bf2f((u16)(bu >> 16)) * s1 + h1;
    t1 = ((t1 >= 0.0f) ? t1 : SLOPE * t1) + bf2f((u16)(ru >> 16));
    float s = t0 + t1;
    float q = t0 * t0 + t1 * t1;
    #pragma unroll
    for (int off = 1; off < 64; off <<= 1){
        s += __shfl_xor(s, off, 64);
        q += __shfl_xor(q, off, 64);
    }
    float mean = s * (1.0f / DH);
    float var  = q * (1.0f / DH) - mean * mean;
    float rstd = rsqrtf(var + EPSF);
    float2 o;
    o.x = (t0 - mean) * rstd;
    o.y = (t1 - mean) * rstd;
    *(float2*)&out[(size_t)node * DH + col] = o;
}

// ---------------- launch ----------------

extern "C" void kernel_launch(void* const* d_in, const int* in_sizes, int n_in,
                              void* d_out, int out_size, void* d_ws, size_t ws_size,
                              hipStream_t stream){
    const float* x    = (const float*)d_in[0];
    const int*   src  = (const int*)d_in[1];
    const int*   dst  = (const int*)d_in[2];
    const float* ew   = (const float*)d_in[3];
    const float* W0   = (const float*)d_in[4];
    const float* b0   = (const float*)d_in[5];
    const float* g0   = (const float*)d_in[6];
    const float* be0  = (const float*)d_in[7];
    const float* W1   = (const float*)d_in[8];
    const float* b1   = (const float*)d_in[9];
    const float* g1   = (const float*)d_in[10];
    const float* be1  = (const float*)d_in[11];
    const float* Wres = (const float*)d_in[12];
    const float* bres = (const float*)d_in[13];
    float* out = (float*)d_out;

    int N = in_sizes[0] / DIN;
    int E = in_sizes[1];
    size_t N128 = (size_t)N * DH;
    float invN = 1.0f / (float)N;

    // workspace layout
    u16* A = (u16*)d_ws;                 // gemm outputs, bf16 [N128]
    u16* B = A + N128;                   // agg outputs, bf16 [N128]
    u16* R = B + N128;                   // residual, bf16 [N128]
    u64* packed = (u64*)(R + N128);      // [N+1]: histogram + ticket word
    u32* ticket = (u32*)&packed[N];
    u64* edata  = packed + N + 1;        // [E] src | coef<<32
    float* dinv = (float*)(edata + E);   // [N]
    int* rowst  = (int*)(dinv + N);      // [N+1] (block-local; +blocksum[i>>10] = global)
    int* slotl  = rowst + N + 1;         // [E]
    float* stats = (float*)(slotl + E);  // 4*DH
    float* sum0 = stats,          *sq0 = stats + DH;
    float* sum1 = stats + 2 * DH, *sq1 = stats + 3 * DH;
    int* blocksum = (int*)(stats + 4 * DH);  // [64]

    int eb8 = (E + 2047) / 2048;
    int gb  = (N + 63) / 64;
    int ab4 = (N + 3) / 4;
    int kb  = (N + 1023) / 1024;
    int rpb = 250;
    int sb  = (N + rpb - 1) / rpb;

    // zero histogram + ticket (DMA node)
    hipMemsetAsync(packed, 0, (size_t)(N + 1) * 8, stream);

    // count (atomic-bound) + gemm0 (compute-bound) co-scheduled in one dispatch
    k_cnt_gemm0<<<eb8 + gb, 256, 0, stream>>>(dst, ew, packed, slotl, E, eb8,
                                              x, W0, Wres, bres, A, R, N);
    k_scan <<<kb, 1024, 0, stream>>>(packed, ticket, dinv, rowst, blocksum, stats, N, E);
    k_place<<<eb8, 256, 0, stream>>>(src, dst, ew, dinv, rowst, blocksum, slotl, edata, E);

    // layer 0
    k_aggregate<<<ab4, 256, 0, stream>>>(A, B, b0, dinv, rowst, blocksum, edata, N);
    k_bnstats  <<<sb, 256, 0, stream>>>(B, sum0, sq0, N, rpb);

    // layer 1 (BN0+leaky+residual fused into gemm1 tile load)
    k_gemm1f   <<<gb, 256, 0, stream>>>(B, R, sum0, sq0, g0, be0, W1, A, N, invN);
    k_aggregate<<<ab4, 256, 0, stream>>>(A, B, b1, dinv, rowst, blocksum, edata, N);
    k_bnstats  <<<sb, 256, 0, stream>>>(B, sum1, sq1, N, rpb);

    // BN1+leaky+residual + layernorm fused
    k_lnf      <<<ab4, 256, 0, stream>>>(B, R, sum1, sq1, g1, be1, out, N, invN);
}